// Round 2
// baseline (755.087 us; speedup 1.0000x reference)
//
#include <hip/hip_runtime.h>

// Problem constants (B=2, T=2048, D=1024, H=16, hd=64)
#define T_SEQ 2048
#define DMODEL 1024
#define NH 16
#define HD 64

// ---------------------------------------------------------------------------
// C[M,N] = A[M,K] @ W[K,N] + bias[N]    (fp32, vector FMA)
// BM=128, BN=64, BK=16, 256 threads, 8x4 micro-tile per thread.
// ---------------------------------------------------------------------------
template<int BM, int BN, int BK>
__global__ __launch_bounds__(256) void gemm_bias_kernel(
    const float* __restrict__ A, const float* __restrict__ W,
    const float* __restrict__ bias, float* __restrict__ C,
    int M, int N, int K)
{
    __shared__ float As[BK][BM];   // transposed A tile: As[k][m]
    __shared__ float Bs[BK][BN];

    const int tid = threadIdx.x;
    const int m0 = blockIdx.y * BM;
    const int n0 = blockIdx.x * BN;

    // compute mapping: 16 row-groups (8 rows) x 16 col-groups (4 cols)
    const int rg = tid >> 4;
    const int cg = tid & 15;

    float acc[8][4];
    #pragma unroll
    for (int i = 0; i < 8; ++i)
        #pragma unroll
        for (int j = 0; j < 4; ++j) acc[i][j] = 0.f;

    // A-load: each thread 2 float4 from one row (row = tid>>1, col = (tid&1)*8)
    const int ar = tid >> 1;
    const int ac = (tid & 1) * 8;
    // B-load: each thread 1 float4 (row = tid>>4, col = (tid&15)*4)
    const int br = tid >> 4;
    const int bc = (tid & 15) * 4;

    for (int k0 = 0; k0 < K; k0 += BK) {
        __syncthreads();
        {
            const float4 a0 = *reinterpret_cast<const float4*>(&A[(size_t)(m0 + ar) * K + k0 + ac]);
            const float4 a1 = *reinterpret_cast<const float4*>(&A[(size_t)(m0 + ar) * K + k0 + ac + 4]);
            // transposed scalar writes: lanes hit distinct banks (ar%32), 2-way max (free)
            As[ac + 0][ar] = a0.x; As[ac + 1][ar] = a0.y;
            As[ac + 2][ar] = a0.z; As[ac + 3][ar] = a0.w;
            As[ac + 4][ar] = a1.x; As[ac + 5][ar] = a1.y;
            As[ac + 6][ar] = a1.z; As[ac + 7][ar] = a1.w;
            *reinterpret_cast<float4*>(&Bs[br][bc]) =
                *reinterpret_cast<const float4*>(&W[(size_t)(k0 + br) * N + n0 + bc]);
        }
        __syncthreads();
        #pragma unroll
        for (int kk = 0; kk < BK; ++kk) {
            const float4 av0 = *reinterpret_cast<const float4*>(&As[kk][rg * 8]);
            const float4 av1 = *reinterpret_cast<const float4*>(&As[kk][rg * 8 + 4]);
            const float4 bv  = *reinterpret_cast<const float4*>(&Bs[kk][cg * 4]);
            const float a[8] = {av0.x, av0.y, av0.z, av0.w, av1.x, av1.y, av1.z, av1.w};
            const float b[4] = {bv.x, bv.y, bv.z, bv.w};
            #pragma unroll
            for (int i = 0; i < 8; ++i)
                #pragma unroll
                for (int j = 0; j < 4; ++j)
                    acc[i][j] = fmaf(a[i], b[j], acc[i][j]);
        }
    }

    const float4 bv = *reinterpret_cast<const float4*>(&bias[n0 + cg * 4]);
    const float bb[4] = {bv.x, bv.y, bv.z, bv.w};
    #pragma unroll
    for (int i = 0; i < 8; ++i) {
        float4 o;
        o.x = acc[i][0] + bb[0];
        o.y = acc[i][1] + bb[1];
        o.z = acc[i][2] + bb[2];
        o.w = acc[i][3] + bb[3];
        *reinterpret_cast<float4*>(&C[(size_t)(m0 + rg * 8 + i) * N + n0 + cg * 4]) = o;
    }
}

// ---------------------------------------------------------------------------
// Sliding-window attention, fp32 flash-style.
// qkv: [B*T, 3*D] (cols 0..D-1 = q, D..2D-1 = k, 2D..3D-1 = v)
// out: [B*T, D]   (head h occupies cols h*64..h*64+63)
// Block = (64-query tile) x (b,h). 256 threads: 4 lanes per query, each lane
// owns a 16-wide slice of hd. Scores: per-lane partial dot + quad butterfly.
// Band window=W -> at most 5 aligned 64-key chunks per 64-query tile.
// ---------------------------------------------------------------------------
__global__ __launch_bounds__(256) void swa_kernel(
    const float* __restrict__ qkv,
    float* __restrict__ out,
    const int* __restrict__ wptr)
{
    const int window = *wptr;
    const int qt = blockIdx.x;        // query tile
    const int bh = blockIdx.y;
    const int b  = bh >> 4;
    const int h  = bh & (NH - 1);

    const int tid = threadIdx.x;
    const int qi  = tid >> 2;         // 0..63 query within tile
    const int sub = tid & 3;          // dim slice sub*16..+15

    const int tq = qt * 64 + qi;
    const size_t qrow = (size_t)(b * T_SEQ + tq) * (3 * DMODEL);
    const int hoff = h * HD;

    __shared__ float Ks[64][HD + 4];
    __shared__ float Vs[64][HD + 4];

    float qv[16];
    {
        const float* qp = &qkv[qrow + hoff + sub * 16];
        #pragma unroll
        for (int i = 0; i < 4; ++i) {
            const float4 t = *reinterpret_cast<const float4*>(qp + i * 4);
            qv[i*4+0] = t.x; qv[i*4+1] = t.y; qv[i*4+2] = t.z; qv[i*4+3] = t.w;
        }
    }

    float ov[16];
    #pragma unroll
    for (int i = 0; i < 16; ++i) ov[i] = 0.f;
    float m = -1e30f, l = 0.f;
    const float scale = 0.125f;       // 1/sqrt(64)

    const int lo = qt * 64 - window;
    const int cstart = (lo <= 0) ? 0 : (lo >> 6);

    // loader mapping: row = tid>>2, cols (tid&3)*16..+15
    const int lr = tid >> 2;
    const int lc = (tid & 3) * 16;

    for (int c = cstart; c <= qt; ++c) {
        __syncthreads();
        {
            const size_t krow = (size_t)(b * T_SEQ + c * 64 + lr) * (3 * DMODEL)
                                + DMODEL + hoff + lc;
            const size_t vrow = krow + DMODEL;
            #pragma unroll
            for (int i = 0; i < 4; ++i) {
                *reinterpret_cast<float4*>(&Ks[lr][lc + i*4]) =
                    *reinterpret_cast<const float4*>(&qkv[krow + i*4]);
                *reinterpret_cast<float4*>(&Vs[lr][lc + i*4]) =
                    *reinterpret_cast<const float4*>(&qkv[vrow + i*4]);
            }
        }
        __syncthreads();

        float s[64];                  // fully unrolled -> stays in VGPRs
        float cmax = -1e30f;
        const int j0 = c * 64;
        #pragma unroll
        for (int kj = 0; kj < 64; ++kj) {
            const float* kp = &Ks[kj][sub * 16];
            float part = 0.f;
            #pragma unroll
            for (int d = 0; d < 16; ++d) part = fmaf(qv[d], kp[d], part);
            part += __shfl_xor(part, 1);
            part += __shfl_xor(part, 2);
            const int diff = tq - (j0 + kj);
            const bool valid = (diff >= 0) && (diff <= window);
            s[kj] = valid ? part * scale : -1e30f;
            cmax = fmaxf(cmax, s[kj]);
        }

        const float m_new = fmaxf(m, cmax);
        const float rf = __expf(m - m_new);
        l *= rf;
        #pragma unroll
        for (int i = 0; i < 16; ++i) ov[i] *= rf;

        #pragma unroll
        for (int kj = 0; kj < 64; ++kj) {
            const float p = (s[kj] > -1e29f) ? __expf(s[kj] - m_new) : 0.f;
            l += p;
            const float* vp = &Vs[kj][sub * 16];
            #pragma unroll
            for (int d = 0; d < 16; ++d) ov[d] = fmaf(p, vp[d], ov[d]);
        }
        m = m_new;
    }

    const float inv_l = 1.f / l;
    float* op = &out[(size_t)(b * T_SEQ + tq) * DMODEL + hoff + sub * 16];
    #pragma unroll
    for (int i = 0; i < 4; ++i) {
        float4 t;
        t.x = ov[i*4+0] * inv_l; t.y = ov[i*4+1] * inv_l;
        t.z = ov[i*4+2] * inv_l; t.w = ov[i*4+3] * inv_l;
        *reinterpret_cast<float4*>(op + i*4) = t;
    }
}

// ---------------------------------------------------------------------------
extern "C" void kernel_launch(void* const* d_in, const int* in_sizes, int n_in,
                              void* d_out, int out_size, void* d_ws, size_t ws_size,
                              hipStream_t stream) {
    (void)in_sizes; (void)n_in; (void)out_size; (void)ws_size;

    const float* x     = (const float*)d_in[0];   // [4096, 1024]
    const float* w_qkv = (const float*)d_in[1];   // [1024, 3072]
    const float* b_qkv = (const float*)d_in[2];   // [3072]
    const float* w_o   = (const float*)d_in[3];   // [1024, 1024]
    const float* b_o   = (const float*)d_in[4];   // [1024]
    const int*   wnd   = (const int*)d_in[5];     // scalar window

    const int M = 2 * T_SEQ;                      // 4096 rows

    // workspace layout: qkv [4096,3072] fp32 (48MB) | att [4096,1024] fp32 (16MB)
    float* qkv = (float*)d_ws;
    float* att = (float*)((char*)d_ws + (size_t)M * 3 * DMODEL * sizeof(float));
    float* out = (float*)d_out;

    dim3 blk(256);

    // 1) qkv = x @ w_qkv + b_qkv
    gemm_bias_kernel<128, 64, 16><<<dim3(3 * DMODEL / 64, M / 128), blk, 0, stream>>>(
        x, w_qkv, b_qkv, qkv, M, 3 * DMODEL, DMODEL);

    // 2) banded attention
    swa_kernel<<<dim3(T_SEQ / 64, 2 * NH), blk, 0, stream>>>(qkv, att, wnd);

    // 3) out = att @ w_o + b_o
    gemm_bias_kernel<128, 64, 16><<<dim3(DMODEL / 64, M / 128), blk, 0, stream>>>(
        att, w_o, b_o, out, M, DMODEL, DMODEL);
}

// Round 4
// 340.161 us; speedup vs baseline: 2.2198x; 2.2198x over previous
//
#include <hip/hip_runtime.h>

// Problem constants (B=2, T=2048, D=1024, H=16, hd=64)
#define T_SEQ 2048
#define DMODEL 1024
#define NH 16
#define HD 64

typedef unsigned short u16;
typedef __attribute__((ext_vector_type(8))) unsigned short u16x8;
typedef __attribute__((ext_vector_type(4))) unsigned short u16x4;
typedef __attribute__((ext_vector_type(8))) short bf16x8;   // MFMA A/B frag (guide-verified type)
typedef __attribute__((ext_vector_type(4))) float f32x4;    // MFMA C/D frag

__device__ __forceinline__ u16 f2bf(float f) {              // RNE float->bf16 bits
    union { float f; unsigned u; } v; v.f = f;
    unsigned r = v.u + 0x7fffu + ((v.u >> 16) & 1u);
    return (u16)(r >> 16);
}
__device__ __forceinline__ float bf2f(u16 u) {
    union { unsigned u; float f; } v; v.u = ((unsigned)u) << 16;
    return v.f;
}

// ---------------------------------------------------------------------------
// Elementwise fp32 -> bf16 convert (for x). 4 elements/thread.
// ---------------------------------------------------------------------------
__global__ __launch_bounds__(256) void convert_kernel(
    const float* __restrict__ in, u16* __restrict__ out, int n)
{
    int idx = (blockIdx.x * 256 + threadIdx.x) * 4;
    if (idx < n) {
        float4 v = *reinterpret_cast<const float4*>(&in[idx]);
        u16x4 o;
        o.x = f2bf(v.x); o.y = f2bf(v.y); o.z = f2bf(v.z); o.w = f2bf(v.w);
        *reinterpret_cast<u16x4*>(&out[idx]) = o;
    }
}

// ---------------------------------------------------------------------------
// in [K][N] fp32 -> out [N][K] bf16 (transpose + convert). 64x64 LDS tiles.
// ---------------------------------------------------------------------------
__global__ __launch_bounds__(256) void transpose_convert_kernel(
    const float* __restrict__ in, u16* __restrict__ out, int K, int N)
{
    __shared__ u16 tile[64][65];          // [n][k], +1 pad
    const int tid = threadIdx.x;
    const int k0 = blockIdx.y * 64, n0 = blockIdx.x * 64;
    const int r  = tid >> 2;              // 0..63
    const int c4 = (tid & 3) * 16;        // 0/16/32/48
    #pragma unroll
    for (int i = 0; i < 4; ++i) {
        float4 v = *reinterpret_cast<const float4*>(&in[(size_t)(k0 + r) * N + n0 + c4 + i * 4]);
        tile[c4 + i*4 + 0][r] = f2bf(v.x);
        tile[c4 + i*4 + 1][r] = f2bf(v.y);
        tile[c4 + i*4 + 2][r] = f2bf(v.z);
        tile[c4 + i*4 + 3][r] = f2bf(v.w);
    }
    __syncthreads();
    u16x8 o0, o1;
    #pragma unroll
    for (int i = 0; i < 8; ++i) o0[i] = tile[r][c4 + i];
    #pragma unroll
    for (int i = 0; i < 8; ++i) o1[i] = tile[r][c4 + 8 + i];
    *reinterpret_cast<u16x8*>(&out[(size_t)(n0 + r) * K + k0 + c4])     = o0;
    *reinterpret_cast<u16x8*>(&out[(size_t)(n0 + r) * K + k0 + c4 + 8]) = o1;
}

// ---------------------------------------------------------------------------
// MFMA GEMM: C[M,N] = A[M,K](bf16) @ BT[N,K](bf16)^T + bias.
// m97-style: 128 x BN tile, BK=32, 256 threads (4 waves 2x2), 16x16x32 MFMA,
// reg-staged LDS (linear layout), bias folded into acc init.
// OUT_BF16: write bf16 (Cb) else fp32 (C).
// ---------------------------------------------------------------------------
template<int BM, int BN, bool OUT_BF16>
__global__ __launch_bounds__(256) void gemm_mfma_kernel(
    const u16* __restrict__ A, const u16* __restrict__ BT,
    const float* __restrict__ bias,
    float* __restrict__ C, u16* __restrict__ Cb,
    int M, int N, int K)
{
    constexpr int BK = 32;
    __shared__ __align__(16) u16 As[BM * BK];
    __shared__ __align__(16) u16 Bs[BN * BK];

    const int tid  = threadIdx.x;
    const int wave = tid >> 6, lane = tid & 63;
    const int m0 = blockIdx.y * BM, n0 = blockIdx.x * BN;

    constexpr int WM = BM / 2, WN = BN / 2;     // wave tile (64 x 64|32)
    constexpr int MF = WM / 16, NF = WN / 16;   // frags per wave
    const int wm = (wave >> 1) * WM, wn = (wave & 1) * WN;
    const int l15 = lane & 15, l4 = lane >> 4;

    f32x4 acc[MF][NF];
    #pragma unroll
    for (int nf = 0; nf < NF; ++nf) {
        const float bv = bias[n0 + wn + nf * 16 + l15];
        #pragma unroll
        for (int mf = 0; mf < MF; ++mf)
            acc[mf][nf] = (f32x4){bv, bv, bv, bv};
    }

    // staging: chunk c (8 bf16 = 16B): row = c>>2, elem off = (c&3)*8
    const int srow = tid >> 2;
    const int soff = (tid & 3) * 8;

    for (int k0 = 0; k0 < K; k0 += BK) {
        bf16x8 a0 = *reinterpret_cast<const bf16x8*>(&A[(size_t)(m0 + srow) * K + k0 + soff]);
        bf16x8 a1 = *reinterpret_cast<const bf16x8*>(&A[(size_t)(m0 + 64 + srow) * K + k0 + soff]);
        bf16x8 b0 = *reinterpret_cast<const bf16x8*>(&BT[(size_t)(n0 + srow) * K + k0 + soff]);
        bf16x8 b1;
        if constexpr (BN == 128)
            b1 = *reinterpret_cast<const bf16x8*>(&BT[(size_t)(n0 + 64 + srow) * K + k0 + soff]);

        __syncthreads();
        *reinterpret_cast<bf16x8*>(&As[(size_t)tid * 8]) = a0;
        *reinterpret_cast<bf16x8*>(&As[(size_t)(tid + 256) * 8]) = a1;
        *reinterpret_cast<bf16x8*>(&Bs[(size_t)tid * 8]) = b0;
        if constexpr (BN == 128)
            *reinterpret_cast<bf16x8*>(&Bs[(size_t)(tid + 256) * 8]) = b1;
        __syncthreads();

        bf16x8 af[MF], bf[NF];
        #pragma unroll
        for (int mf = 0; mf < MF; ++mf)
            af[mf] = *reinterpret_cast<const bf16x8*>(&As[(wm + mf * 16 + l15) * BK + l4 * 8]);
        #pragma unroll
        for (int nf = 0; nf < NF; ++nf)
            bf[nf] = *reinterpret_cast<const bf16x8*>(&Bs[(wn + nf * 16 + l15) * BK + l4 * 8]);
        #pragma unroll
        for (int mf = 0; mf < MF; ++mf)
            #pragma unroll
            for (int nf = 0; nf < NF; ++nf)
                acc[mf][nf] = __builtin_amdgcn_mfma_f32_16x16x32_bf16(af[mf], bf[nf], acc[mf][nf], 0, 0, 0);
    }

    #pragma unroll
    for (int mf = 0; mf < MF; ++mf)
        #pragma unroll
        for (int nf = 0; nf < NF; ++nf) {
            const int col = n0 + wn + nf * 16 + l15;
            #pragma unroll
            for (int r = 0; r < 4; ++r) {
                const int row = m0 + wm + mf * 16 + l4 * 4 + r;
                if constexpr (OUT_BF16) Cb[(size_t)row * N + col] = f2bf(acc[mf][nf][r]);
                else                    C [(size_t)row * N + col] = acc[mf][nf][r];
            }
        }
}

// ---------------------------------------------------------------------------
// Sliding-window attention, fp32 compute, bf16 I/O.
// qkv: [B*T][3*D] bf16 ; out: [B*T][D] bf16
// Block = (64-query tile) x (b,h); 4 lanes/query, 16-wide hd slices.
// ---------------------------------------------------------------------------
__global__ __launch_bounds__(256) void swa_kernel(
    const u16* __restrict__ qkv, u16* __restrict__ out,
    const int* __restrict__ wptr)
{
    const int window = *wptr;
    const int qt = blockIdx.x;
    const int bh = blockIdx.y;
    const int b  = bh >> 4;
    const int h  = bh & (NH - 1);

    const int tid = threadIdx.x;
    const int qi  = tid >> 2;
    const int sub = tid & 3;

    const int tq = qt * 64 + qi;
    const size_t qrow = (size_t)(b * T_SEQ + tq) * (3 * DMODEL);
    const int hoff = h * HD;

    __shared__ float Ks[64][HD + 4];
    __shared__ float Vs[64][HD + 4];

    float qv[16];
    {
        const u16* qp = &qkv[qrow + hoff + sub * 16];
        u16x8 q0 = *reinterpret_cast<const u16x8*>(qp);
        u16x8 q1 = *reinterpret_cast<const u16x8*>(qp + 8);
        #pragma unroll
        for (int i = 0; i < 8; ++i) { qv[i] = bf2f(q0[i]); qv[8 + i] = bf2f(q1[i]); }
    }

    float ov[16];
    #pragma unroll
    for (int i = 0; i < 16; ++i) ov[i] = 0.f;
    float m = -1e30f, l = 0.f;
    const float scale = 0.125f;

    const int lo = qt * 64 - window;
    const int cstart = (lo <= 0) ? 0 : (lo >> 6);

    const int lr = tid >> 2;
    const int lc = (tid & 3) * 16;

    for (int c = cstart; c <= qt; ++c) {
        __syncthreads();
        {
            const size_t krow = (size_t)(b * T_SEQ + c * 64 + lr) * (3 * DMODEL)
                                + DMODEL + hoff + lc;
            u16x8 ka = *reinterpret_cast<const u16x8*>(&qkv[krow]);
            u16x8 kb = *reinterpret_cast<const u16x8*>(&qkv[krow + 8]);
            u16x8 va = *reinterpret_cast<const u16x8*>(&qkv[krow + DMODEL]);
            u16x8 vb = *reinterpret_cast<const u16x8*>(&qkv[krow + DMODEL + 8]);
            #pragma unroll
            for (int i = 0; i < 2; ++i) {
                float4 kf, vf;
                kf.x = bf2f(ka[i*4+0]); kf.y = bf2f(ka[i*4+1]);
                kf.z = bf2f(ka[i*4+2]); kf.w = bf2f(ka[i*4+3]);
                vf.x = bf2f(va[i*4+0]); vf.y = bf2f(va[i*4+1]);
                vf.z = bf2f(va[i*4+2]); vf.w = bf2f(va[i*4+3]);
                *reinterpret_cast<float4*>(&Ks[lr][lc + i*4]) = kf;
                *reinterpret_cast<float4*>(&Vs[lr][lc + i*4]) = vf;
            }
            #pragma unroll
            for (int i = 0; i < 2; ++i) {
                float4 kf, vf;
                kf.x = bf2f(kb[i*4+0]); kf.y = bf2f(kb[i*4+1]);
                kf.z = bf2f(kb[i*4+2]); kf.w = bf2f(kb[i*4+3]);
                vf.x = bf2f(vb[i*4+0]); vf.y = bf2f(vb[i*4+1]);
                vf.z = bf2f(vb[i*4+2]); vf.w = bf2f(vb[i*4+3]);
                *reinterpret_cast<float4*>(&Ks[lr][lc + 8 + i*4]) = kf;
                *reinterpret_cast<float4*>(&Vs[lr][lc + 8 + i*4]) = vf;
            }
        }
        __syncthreads();

        float s[64];
        float cmax = -1e30f;
        const int j0 = c * 64;
        #pragma unroll
        for (int kj = 0; kj < 64; ++kj) {
            const float* kp = &Ks[kj][sub * 16];
            float part = 0.f;
            #pragma unroll
            for (int d = 0; d < 16; ++d) part = fmaf(qv[d], kp[d], part);
            part += __shfl_xor(part, 1);
            part += __shfl_xor(part, 2);
            const int diff = tq - (j0 + kj);
            const bool valid = (diff >= 0) && (diff <= window);
            s[kj] = valid ? part * scale : -1e30f;
            cmax = fmaxf(cmax, s[kj]);
        }

        const float m_new = fmaxf(m, cmax);
        const float rf = __expf(m - m_new);
        l *= rf;
        #pragma unroll
        for (int i = 0; i < 16; ++i) ov[i] *= rf;

        #pragma unroll
        for (int kj = 0; kj < 64; ++kj) {
            const float p = (s[kj] > -1e29f) ? __expf(s[kj] - m_new) : 0.f;
            l += p;
            const float* vp = &Vs[kj][sub * 16];
            #pragma unroll
            for (int d = 0; d < 16; ++d) ov[d] = fmaf(p, vp[d], ov[d]);
        }
        m = m_new;
    }

    const float inv_l = 1.f / l;
    u16x8 o0, o1;
    #pragma unroll
    for (int i = 0; i < 8; ++i) {
        o0[i] = f2bf(ov[i] * inv_l);
        o1[i] = f2bf(ov[8 + i] * inv_l);
    }
    u16* op = &out[(size_t)(b * T_SEQ + tq) * DMODEL + hoff + sub * 16];
    *reinterpret_cast<u16x8*>(op)     = o0;
    *reinterpret_cast<u16x8*>(op + 8) = o1;
}

// ---------------------------------------------------------------------------
extern "C" void kernel_launch(void* const* d_in, const int* in_sizes, int n_in,
                              void* d_out, int out_size, void* d_ws, size_t ws_size,
                              hipStream_t stream) {
    (void)in_sizes; (void)n_in; (void)out_size; (void)ws_size;

    const float* x     = (const float*)d_in[0];   // [4096, 1024]
    const float* w_qkv = (const float*)d_in[1];   // [1024, 3072]
    const float* b_qkv = (const float*)d_in[2];   // [3072]
    const float* w_o   = (const float*)d_in[3];   // [1024, 1024]
    const float* b_o   = (const float*)d_in[4];   // [1024]
    const int*   wnd   = (const int*)d_in[5];

    const int M = 2 * T_SEQ;                      // 4096

    // ws layout (bytes): qkvb 24M | attb 8M | xb 8M | wqkvT 6M | woT 2M = 48 MB
    char* w = (char*)d_ws;
    u16* qkvb  = (u16*)(w);
    u16* attb  = (u16*)(w + 24u * 1024 * 1024);
    u16* xb    = (u16*)(w + 32u * 1024 * 1024);
    u16* wqkvT = (u16*)(w + 40u * 1024 * 1024);
    u16* woT   = (u16*)(w + 46u * 1024 * 1024);

    dim3 blk(256);

    // converts (independent)
    convert_kernel<<<dim3((M * DMODEL / 4 + 255) / 256), blk, 0, stream>>>(x, xb, M * DMODEL);
    transpose_convert_kernel<<<dim3(3 * DMODEL / 64, DMODEL / 64), blk, 0, stream>>>(
        w_qkv, wqkvT, DMODEL, 3 * DMODEL);
    transpose_convert_kernel<<<dim3(DMODEL / 64, DMODEL / 64), blk, 0, stream>>>(
        w_o, woT, DMODEL, DMODEL);

    // 1) qkv(bf16) = x @ w_qkv + b_qkv
    gemm_mfma_kernel<128, 128, true><<<dim3(3 * DMODEL / 128, M / 128), blk, 0, stream>>>(
        xb, wqkvT, b_qkv, nullptr, qkvb, M, 3 * DMODEL, DMODEL);

    // 2) banded attention (bf16 I/O)
    swa_kernel<<<dim3(T_SEQ / 64, 2 * NH), blk, 0, stream>>>(qkvb, attb, wnd);

    // 3) out(fp32) = att @ w_o + b_o
    gemm_mfma_kernel<128, 64, false><<<dim3(DMODEL / 64, M / 128), blk, 0, stream>>>(
        attb, woT, b_o, (float*)d_out, nullptr, M, DMODEL, DMODEL);
}

// Round 7
// 179.274 us; speedup vs baseline: 4.2119x; 1.8974x over previous
//
#include <hip/hip_runtime.h>

// Problem constants (B=2, T=2048, D=1024, H=16, hd=64)
#define T_SEQ 2048
#define DMODEL 1024
#define NH 16
#define HD 64

typedef unsigned short u16;
typedef short s16;
typedef __attribute__((ext_vector_type(8))) unsigned short u16x8;
typedef __attribute__((ext_vector_type(4))) unsigned short u16x4;
typedef __attribute__((ext_vector_type(8))) short bf16x8;   // MFMA A/B frag
typedef __attribute__((ext_vector_type(4))) float f32x4;    // MFMA C/D frag

__device__ __forceinline__ u16 f2bf(float f) {              // RNE float->bf16 bits
    union { float f; unsigned u; } v; v.f = f;
    unsigned r = v.u + 0x7fffu + ((v.u >> 16) & 1u);
    return (u16)(r >> 16);
}
__device__ __forceinline__ float bf2f(u16 u) {
    union { unsigned u; float f; } v; v.u = ((unsigned)u) << 16;
    return v.f;
}

// ---------------------------------------------------------------------------
// Elementwise fp32 -> bf16 convert (for x). 4 elements/thread.
// ---------------------------------------------------------------------------
__global__ __launch_bounds__(256) void convert_kernel(
    const float* __restrict__ in, u16* __restrict__ out, int n)
{
    int idx = (blockIdx.x * 256 + threadIdx.x) * 4;
    if (idx < n) {
        float4 v = *reinterpret_cast<const float4*>(&in[idx]);
        u16x4 o;
        o.x = f2bf(v.x); o.y = f2bf(v.y); o.z = f2bf(v.z); o.w = f2bf(v.w);
        *reinterpret_cast<u16x4*>(&out[idx]) = o;
    }
}

// ---------------------------------------------------------------------------
// in [K][N] fp32 -> out [N][K] bf16 (transpose + convert). 64x64 LDS tiles.
// ---------------------------------------------------------------------------
__global__ __launch_bounds__(256) void transpose_convert_kernel(
    const float* __restrict__ in, u16* __restrict__ out, int K, int N)
{
    __shared__ u16 tile[64][65];          // [n][k], +1 pad
    const int tid = threadIdx.x;
    const int k0 = blockIdx.y * 64, n0 = blockIdx.x * 64;
    const int r  = tid >> 2;              // 0..63
    const int c4 = (tid & 3) * 16;        // 0/16/32/48
    #pragma unroll
    for (int i = 0; i < 4; ++i) {
        float4 v = *reinterpret_cast<const float4*>(&in[(size_t)(k0 + r) * N + n0 + c4 + i * 4]);
        tile[c4 + i*4 + 0][r] = f2bf(v.x);
        tile[c4 + i*4 + 1][r] = f2bf(v.y);
        tile[c4 + i*4 + 2][r] = f2bf(v.z);
        tile[c4 + i*4 + 3][r] = f2bf(v.w);
    }
    __syncthreads();
    u16x8 o0, o1;
    #pragma unroll
    for (int i = 0; i < 8; ++i) o0[i] = tile[r][c4 + i];
    #pragma unroll
    for (int i = 0; i < 8; ++i) o1[i] = tile[r][c4 + 8 + i];
    *reinterpret_cast<u16x8*>(&out[(size_t)(n0 + r) * K + k0 + c4])     = o0;
    *reinterpret_cast<u16x8*>(&out[(size_t)(n0 + r) * K + k0 + c4 + 8]) = o1;
}

// ---------------------------------------------------------------------------
// MFMA GEMM: C[M,N] = A[M,K](bf16) @ BT[N,K](bf16)^T + bias.  (unchanged)
// ---------------------------------------------------------------------------
template<int BM, int BN, bool OUT_BF16>
__global__ __launch_bounds__(256) void gemm_mfma_kernel(
    const u16* __restrict__ A, const u16* __restrict__ BT,
    const float* __restrict__ bias,
    float* __restrict__ C, u16* __restrict__ Cb,
    int M, int N, int K)
{
    constexpr int BK = 32;
    __shared__ __align__(16) u16 As[BM * BK];
    __shared__ __align__(16) u16 Bs[BN * BK];

    const int tid  = threadIdx.x;
    const int wave = tid >> 6, lane = tid & 63;
    const int m0 = blockIdx.y * BM, n0 = blockIdx.x * BN;

    constexpr int WM = BM / 2, WN = BN / 2;
    constexpr int MF = WM / 16, NF = WN / 16;
    const int wm = (wave >> 1) * WM, wn = (wave & 1) * WN;
    const int l15 = lane & 15, l4 = lane >> 4;

    f32x4 acc[MF][NF];
    #pragma unroll
    for (int nf = 0; nf < NF; ++nf) {
        const float bv = bias[n0 + wn + nf * 16 + l15];
        #pragma unroll
        for (int mf = 0; mf < MF; ++mf)
            acc[mf][nf] = (f32x4){bv, bv, bv, bv};
    }

    const int srow = tid >> 2;
    const int soff = (tid & 3) * 8;

    for (int k0 = 0; k0 < K; k0 += BK) {
        bf16x8 a0 = *reinterpret_cast<const bf16x8*>(&A[(size_t)(m0 + srow) * K + k0 + soff]);
        bf16x8 a1 = *reinterpret_cast<const bf16x8*>(&A[(size_t)(m0 + 64 + srow) * K + k0 + soff]);
        bf16x8 b0 = *reinterpret_cast<const bf16x8*>(&BT[(size_t)(n0 + srow) * K + k0 + soff]);
        bf16x8 b1;
        if constexpr (BN == 128)
            b1 = *reinterpret_cast<const bf16x8*>(&BT[(size_t)(n0 + 64 + srow) * K + k0 + soff]);

        __syncthreads();
        *reinterpret_cast<bf16x8*>(&As[(size_t)tid * 8]) = a0;
        *reinterpret_cast<bf16x8*>(&As[(size_t)(tid + 256) * 8]) = a1;
        *reinterpret_cast<bf16x8*>(&Bs[(size_t)tid * 8]) = b0;
        if constexpr (BN == 128)
            *reinterpret_cast<bf16x8*>(&Bs[(size_t)(tid + 256) * 8]) = b1;
        __syncthreads();

        bf16x8 af[MF], bf[NF];
        #pragma unroll
        for (int mf = 0; mf < MF; ++mf)
            af[mf] = *reinterpret_cast<const bf16x8*>(&As[(wm + mf * 16 + l15) * BK + l4 * 8]);
        #pragma unroll
        for (int nf = 0; nf < NF; ++nf)
            bf[nf] = *reinterpret_cast<const bf16x8*>(&Bs[(wn + nf * 16 + l15) * BK + l4 * 8]);
        #pragma unroll
        for (int mf = 0; mf < MF; ++mf)
            #pragma unroll
            for (int nf = 0; nf < NF; ++nf)
                acc[mf][nf] = __builtin_amdgcn_mfma_f32_16x16x32_bf16(af[mf], bf[nf], acc[mf][nf], 0, 0, 0);
    }

    #pragma unroll
    for (int mf = 0; mf < MF; ++mf)
        #pragma unroll
        for (int nf = 0; nf < NF; ++nf) {
            const int col = n0 + wn + nf * 16 + l15;
            #pragma unroll
            for (int r = 0; r < 4; ++r) {
                const int row = m0 + wm + mf * 16 + l4 * 4 + r;
                if constexpr (OUT_BF16) Cb[(size_t)row * N + col] = f2bf(acc[mf][nf][r]);
                else                    C [(size_t)row * N + col] = acc[mf][nf][r];
            }
        }
}

// ---------------------------------------------------------------------------
// MFMA sliding-window attention.
// qkv [B*T][3D] bf16; out [B*T][D] bf16. Block = 256 thr (4 waves) per
// (64-query tile, b, h). Wave w owns queries w*16..w*16+15.
// Per 64-key chunk: QK^T (8 MFMA/wave) -> online softmax in C/D layout
// (4-step shfl_xor tree over the 16 key-lanes) -> P(bf16)->LDS -> PV
// (8 MFMA/wave) with V staged transposed Vt[hd][key].
// All LDS XOR-swizzled: elem ^= (row&7)<<3  (Guideline 4: 128B rows are
// otherwise a 16-way bank conflict on b128 frag reads).
// ---------------------------------------------------------------------------
__global__ __launch_bounds__(256) void swa_mfma_kernel(
    const u16* __restrict__ qkv, u16* __restrict__ out,
    const int* __restrict__ wptr)
{
    const int window = *wptr;
    const int qt = blockIdx.x;
    const int bh = blockIdx.y;
    const int b  = bh >> 4;
    const int h  = bh & (NH - 1);

    const int tid  = threadIdx.x;
    const int wave = tid >> 6, lane = tid & 63;
    const int l15  = lane & 15, l4 = lane >> 4;
    const int hoff = h * HD;

    __shared__ __align__(16) s16 Ks[64 * 64];   // [key][hd], swizzled
    __shared__ __align__(16) s16 Vt[64 * 64];   // [hd][key], swizzled
    __shared__ __align__(16) s16 Ps[64 * 64];   // [q][key],  swizzled

    // swizzled u16-element index within a [64][64] tile (row stride 128 B)
    auto swz = [](int row, int col) { return (row * 64 + col) ^ ((row & 7) << 3); };

    // Q fragments held in registers: A-frag rows = wave*16 + l15
    const size_t qgrow = (size_t)(b * T_SEQ + qt * 64 + wave * 16 + l15) * (3 * DMODEL) + hoff;
    const bf16x8 qf0 = *reinterpret_cast<const bf16x8*>(&qkv[qgrow + l4 * 8]);
    const bf16x8 qf1 = *reinterpret_cast<const bf16x8*>(&qkv[qgrow + 32 + l4 * 8]);

    f32x4 oacc[4];
    #pragma unroll
    for (int nf = 0; nf < 4; ++nf) oacc[nf] = (f32x4){0.f, 0.f, 0.f, 0.f};
    float m[4] = {-1e30f, -1e30f, -1e30f, -1e30f};
    float l[4] = {0.f, 0.f, 0.f, 0.f};

    const int lo = qt * 64 - window;
    const int cstart = (lo <= 0) ? 0 : (lo >> 6);

    // staging: thread -> (row kr, 8-col chunk kc), two passes of 32 rows
    const int kr = tid >> 3;
    const int kc = (tid & 7) * 8;

    for (int c = cstart; c <= qt; ++c) {
        const int j0 = c * 64;
        __syncthreads();   // protect Ks/Vt from overwrite while others read
        #pragma unroll
        for (int pass = 0; pass < 2; ++pass) {
            const int row = kr + pass * 32;
            const size_t g = (size_t)(b * T_SEQ + j0 + row) * (3 * DMODEL) + hoff + kc;
            const bf16x8 kv8 = *reinterpret_cast<const bf16x8*>(&qkv[g + DMODEL]);
            const bf16x8 vv8 = *reinterpret_cast<const bf16x8*>(&qkv[g + 2 * DMODEL]);
            *reinterpret_cast<bf16x8*>(&Ks[swz(row, kc)]) = kv8;
            #pragma unroll
            for (int i = 0; i < 8; ++i)
                Vt[swz(kc + i, row)] = vv8[i];   // transpose scatter
        }
        __syncthreads();

        // ---- S = Q @ K^T (strip: 16 queries x 64 keys) ----
        f32x4 sacc[4];
        #pragma unroll
        for (int nf = 0; nf < 4; ++nf) sacc[nf] = (f32x4){0.f, 0.f, 0.f, 0.f};
        #pragma unroll
        for (int nf = 0; nf < 4; ++nf) {
            const bf16x8 kf0 = *reinterpret_cast<const bf16x8*>(&Ks[swz(nf * 16 + l15, l4 * 8)]);
            const bf16x8 kf1 = *reinterpret_cast<const bf16x8*>(&Ks[swz(nf * 16 + l15, 32 + l4 * 8)]);
            sacc[nf] = __builtin_amdgcn_mfma_f32_16x16x32_bf16(qf0, kf0, sacc[nf], 0, 0, 0);
            sacc[nf] = __builtin_amdgcn_mfma_f32_16x16x32_bf16(qf1, kf1, sacc[nf], 0, 0, 0);
        }

        // ---- online softmax; C/D rows: iq_loc = wave*16 + l4*4 + r ----
        float p[4][4];
        #pragma unroll
        for (int r = 0; r < 4; ++r) {
            const int iq = qt * 64 + wave * 16 + l4 * 4 + r;
            float rmax = -1e30f;
            #pragma unroll
            for (int nf = 0; nf < 4; ++nf) {
                const int diff = iq - (j0 + nf * 16 + l15);
                const bool valid = (diff >= 0) && (diff <= window);
                const float s = valid ? sacc[nf][r] * 0.125f : -1e30f;
                p[r][nf] = s;
                rmax = fmaxf(rmax, s);
            }
            rmax = fmaxf(rmax, __shfl_xor(rmax, 1));
            rmax = fmaxf(rmax, __shfl_xor(rmax, 2));
            rmax = fmaxf(rmax, __shfl_xor(rmax, 4));
            rmax = fmaxf(rmax, __shfl_xor(rmax, 8));
            const float mn = fmaxf(m[r], rmax);
            const float rf = __expf(m[r] - mn);
            float rs = 0.f;
            #pragma unroll
            for (int nf = 0; nf < 4; ++nf) {
                const float e = __expf(p[r][nf] - mn);   // masked -> exp(-huge) = 0
                p[r][nf] = e;
                rs += e;
            }
            rs += __shfl_xor(rs, 1);
            rs += __shfl_xor(rs, 2);
            rs += __shfl_xor(rs, 4);
            rs += __shfl_xor(rs, 8);
            l[r] = l[r] * rf + rs;
            m[r] = mn;
            #pragma unroll
            for (int nf = 0; nf < 4; ++nf) oacc[nf][r] *= rf;
            #pragma unroll
            for (int nf = 0; nf < 4; ++nf)
                Ps[swz(wave * 16 + l4 * 4 + r, nf * 16 + l15)] = (s16)f2bf(p[r][nf]);
        }
        __syncthreads();   // P visible before PV frag reads (safe ordering)

        // ---- O += P @ V  (A = own strip of Ps, B = Vt rows = hd) ----
        #pragma unroll
        for (int ks = 0; ks < 2; ++ks) {
            const bf16x8 pa = *reinterpret_cast<const bf16x8*>(&Ps[swz(wave * 16 + l15, ks * 32 + l4 * 8)]);
            #pragma unroll
            for (int nf = 0; nf < 4; ++nf) {
                const bf16x8 vf = *reinterpret_cast<const bf16x8*>(&Vt[swz(nf * 16 + l15, ks * 32 + l4 * 8)]);
                oacc[nf] = __builtin_amdgcn_mfma_f32_16x16x32_bf16(pa, vf, oacc[nf], 0, 0, 0);
            }
        }
    }

    // ---- epilogue: normalize, write bf16 ----
    #pragma unroll
    for (int r = 0; r < 4; ++r) {
        const float inv = 1.f / l[r];
        const size_t orow = (size_t)(b * T_SEQ + qt * 64 + wave * 16 + l4 * 4 + r) * DMODEL + hoff;
        #pragma unroll
        for (int nf = 0; nf < 4; ++nf)
            out[orow + nf * 16 + l15] = f2bf(oacc[nf][r] * inv);
    }
}

// ---------------------------------------------------------------------------
extern "C" void kernel_launch(void* const* d_in, const int* in_sizes, int n_in,
                              void* d_out, int out_size, void* d_ws, size_t ws_size,
                              hipStream_t stream) {
    (void)in_sizes; (void)n_in; (void)out_size; (void)ws_size;

    const float* x     = (const float*)d_in[0];   // [4096, 1024]
    const float* w_qkv = (const float*)d_in[1];   // [1024, 3072]
    const float* b_qkv = (const float*)d_in[2];   // [3072]
    const float* w_o   = (const float*)d_in[3];   // [1024, 1024]
    const float* b_o   = (const float*)d_in[4];   // [1024]
    const int*   wnd   = (const int*)d_in[5];

    const int M = 2 * T_SEQ;                      // 4096

    // ws layout (bytes): qkvb 24M | attb 8M | xb 8M | wqkvT 6M | woT 2M = 48 MB
    char* w = (char*)d_ws;
    u16* qkvb  = (u16*)(w);
    u16* attb  = (u16*)(w + 24u * 1024 * 1024);
    u16* xb    = (u16*)(w + 32u * 1024 * 1024);
    u16* wqkvT = (u16*)(w + 40u * 1024 * 1024);
    u16* woT   = (u16*)(w + 46u * 1024 * 1024);

    dim3 blk(256);

    // converts (independent)
    convert_kernel<<<dim3((M * DMODEL / 4 + 255) / 256), blk, 0, stream>>>(x, xb, M * DMODEL);
    transpose_convert_kernel<<<dim3(3 * DMODEL / 64, DMODEL / 64), blk, 0, stream>>>(
        w_qkv, wqkvT, DMODEL, 3 * DMODEL);
    transpose_convert_kernel<<<dim3(DMODEL / 64, DMODEL / 64), blk, 0, stream>>>(
        w_o, woT, DMODEL, DMODEL);

    // 1) qkv(bf16) = x @ w_qkv + b_qkv
    gemm_mfma_kernel<128, 128, true><<<dim3(3 * DMODEL / 128, M / 128), blk, 0, stream>>>(
        xb, wqkvT, b_qkv, nullptr, qkvb, M, 3 * DMODEL, DMODEL);

    // 2) banded attention (MFMA)
    swa_mfma_kernel<<<dim3(T_SEQ / 64, 2 * NH), blk, 0, stream>>>(qkvb, attb, wnd);

    // 3) out(fp32) = att @ w_o + b_o
    gemm_mfma_kernel<128, 64, false><<<dim3(DMODEL / 64, M / 128), blk, 0, stream>>>(
        attb, woT, b_o, (float*)d_out, nullptr, M, DMODEL, DMODEL);
}

// Round 8
// 176.647 us; speedup vs baseline: 4.2745x; 1.0149x over previous
//
#include <hip/hip_runtime.h>

// Problem constants (B=2, T=2048, D=1024, H=16, hd=64)
#define T_SEQ 2048
#define DMODEL 1024
#define NH 16
#define HD 64

typedef unsigned short u16;
typedef short s16;
typedef __attribute__((ext_vector_type(8))) unsigned short u16x8;
typedef __attribute__((ext_vector_type(4))) unsigned short u16x4;
typedef __attribute__((ext_vector_type(8))) short bf16x8;   // MFMA A/B frag
typedef __attribute__((ext_vector_type(4))) float f32x4;    // MFMA C/D frag

__device__ __forceinline__ u16 f2bf(float f) {              // RNE float->bf16 bits
    union { float f; unsigned u; } v; v.f = f;
    unsigned r = v.u + 0x7fffu + ((v.u >> 16) & 1u);
    return (u16)(r >> 16);
}
__device__ __forceinline__ float bf2f(u16 u) {
    union { unsigned u; float f; } v; v.u = ((unsigned)u) << 16;
    return v.f;
}

// Async global->LDS 16B copy. Per-lane GLOBAL src is allowed; LDS dest is
// wave-uniform base + lane*16 (our linear layouts satisfy this exactly).
__device__ __forceinline__ void gl_lds16(const u16* g, u16* l) {
    __builtin_amdgcn_global_load_lds(
        (const __attribute__((address_space(1))) unsigned int*)g,
        (__attribute__((address_space(3))) unsigned int*)l, 16, 0, 0);
}

// ---------------------------------------------------------------------------
// Elementwise fp32 -> bf16 convert (for x). 4 elements/thread.
// ---------------------------------------------------------------------------
__global__ __launch_bounds__(256) void convert_kernel(
    const float* __restrict__ in, u16* __restrict__ out, int n)
{
    int idx = (blockIdx.x * 256 + threadIdx.x) * 4;
    if (idx < n) {
        float4 v = *reinterpret_cast<const float4*>(&in[idx]);
        u16x4 o;
        o.x = f2bf(v.x); o.y = f2bf(v.y); o.z = f2bf(v.z); o.w = f2bf(v.w);
        *reinterpret_cast<u16x4*>(&out[idx]) = o;
    }
}

// ---------------------------------------------------------------------------
// in [K][N] fp32 -> out [N][K] bf16 (transpose + convert). 64x64 LDS tiles.
// ---------------------------------------------------------------------------
__global__ __launch_bounds__(256) void transpose_convert_kernel(
    const float* __restrict__ in, u16* __restrict__ out, int K, int N)
{
    __shared__ u16 tile[64][65];          // [n][k], +1 pad
    const int tid = threadIdx.x;
    const int k0 = blockIdx.y * 64, n0 = blockIdx.x * 64;
    const int r  = tid >> 2;              // 0..63
    const int c4 = (tid & 3) * 16;        // 0/16/32/48
    #pragma unroll
    for (int i = 0; i < 4; ++i) {
        float4 v = *reinterpret_cast<const float4*>(&in[(size_t)(k0 + r) * N + n0 + c4 + i * 4]);
        tile[c4 + i*4 + 0][r] = f2bf(v.x);
        tile[c4 + i*4 + 1][r] = f2bf(v.y);
        tile[c4 + i*4 + 2][r] = f2bf(v.z);
        tile[c4 + i*4 + 3][r] = f2bf(v.w);
    }
    __syncthreads();
    u16x8 o0, o1;
    #pragma unroll
    for (int i = 0; i < 8; ++i) o0[i] = tile[r][c4 + i];
    #pragma unroll
    for (int i = 0; i < 8; ++i) o1[i] = tile[r][c4 + 8 + i];
    *reinterpret_cast<u16x8*>(&out[(size_t)(n0 + r) * K + k0 + c4])     = o0;
    *reinterpret_cast<u16x8*>(&out[(size_t)(n0 + r) * K + k0 + c4 + 8]) = o1;
}

// ---------------------------------------------------------------------------
// MFMA GEMM: C[M,N] = A[M,K](bf16) @ BT[N,K](bf16)^T + bias.
// 128 x BN tile, BK=32, 256 threads (4 waves 2x2), 16x16x32 MFMA.
// Staging via global_load_lds 16B (m97 pattern): linear LDS, 2 barriers/K-step.
// ---------------------------------------------------------------------------
template<int BM, int BN, bool OUT_BF16>
__global__ __launch_bounds__(256) void gemm_mfma_kernel(
    const u16* __restrict__ A, const u16* __restrict__ BT,
    const float* __restrict__ bias,
    float* __restrict__ C, u16* __restrict__ Cb,
    int M, int N, int K)
{
    constexpr int BK = 32;
    __shared__ __align__(16) u16 As[BM * BK];
    __shared__ __align__(16) u16 Bs[BN * BK];

    const int tid  = threadIdx.x;
    const int wave = tid >> 6, lane = tid & 63;
    const int m0 = blockIdx.y * BM, n0 = blockIdx.x * BN;

    constexpr int WM = BM / 2, WN = BN / 2;
    constexpr int MF = WM / 16, NF = WN / 16;
    const int wm = (wave >> 1) * WM, wn = (wave & 1) * WN;
    const int l15 = lane & 15, l4 = lane >> 4;

    f32x4 acc[MF][NF];
    #pragma unroll
    for (int nf = 0; nf < NF; ++nf) {
        const float bv = bias[n0 + wn + nf * 16 + l15];
        #pragma unroll
        for (int mf = 0; mf < MF; ++mf)
            acc[mf][nf] = (f32x4){bv, bv, bv, bv};
    }

    // staging map: thread -> (row tid>>2, col-chunk (tid&3)*8); LDS linear in tid.
    const int srow = tid >> 2;
    const int soff = (tid & 3) * 8;

    for (int k0 = 0; k0 < K; k0 += BK) {
        __syncthreads();   // previous iteration's frag reads complete
        gl_lds16(&A[(size_t)(m0 + srow) * K + k0 + soff],       &As[(size_t)tid * 8]);
        gl_lds16(&A[(size_t)(m0 + 64 + srow) * K + k0 + soff],  &As[(size_t)(tid + 256) * 8]);
        gl_lds16(&BT[(size_t)(n0 + srow) * K + k0 + soff],      &Bs[(size_t)tid * 8]);
        if constexpr (BN == 128)
            gl_lds16(&BT[(size_t)(n0 + 64 + srow) * K + k0 + soff], &Bs[(size_t)(tid + 256) * 8]);
        __syncthreads();   // compiler drains vmcnt(0) before barrier -> LDS valid

        bf16x8 af[MF], bf[NF];
        #pragma unroll
        for (int mf = 0; mf < MF; ++mf)
            af[mf] = *reinterpret_cast<const bf16x8*>(&As[(wm + mf * 16 + l15) * BK + l4 * 8]);
        #pragma unroll
        for (int nf = 0; nf < NF; ++nf)
            bf[nf] = *reinterpret_cast<const bf16x8*>(&Bs[(wn + nf * 16 + l15) * BK + l4 * 8]);
        #pragma unroll
        for (int mf = 0; mf < MF; ++mf)
            #pragma unroll
            for (int nf = 0; nf < NF; ++nf)
                acc[mf][nf] = __builtin_amdgcn_mfma_f32_16x16x32_bf16(af[mf], bf[nf], acc[mf][nf], 0, 0, 0);
    }

    #pragma unroll
    for (int mf = 0; mf < MF; ++mf)
        #pragma unroll
        for (int nf = 0; nf < NF; ++nf) {
            const int col = n0 + wn + nf * 16 + l15;
            #pragma unroll
            for (int r = 0; r < 4; ++r) {
                const int row = m0 + wm + mf * 16 + l4 * 4 + r;
                if constexpr (OUT_BF16) Cb[(size_t)row * N + col] = f2bf(acc[mf][nf][r]);
                else                    C [(size_t)row * N + col] = acc[mf][nf][r];
            }
        }
}

// ---------------------------------------------------------------------------
// MFMA sliding-window attention.  (unchanged from round 4 — verified)
// ---------------------------------------------------------------------------
__global__ __launch_bounds__(256) void swa_mfma_kernel(
    const u16* __restrict__ qkv, u16* __restrict__ out,
    const int* __restrict__ wptr)
{
    const int window = *wptr;
    const int qt = blockIdx.x;
    const int bh = blockIdx.y;
    const int b  = bh >> 4;
    const int h  = bh & (NH - 1);

    const int tid  = threadIdx.x;
    const int wave = tid >> 6, lane = tid & 63;
    const int l15  = lane & 15, l4 = lane >> 4;
    const int hoff = h * HD;

    __shared__ __align__(16) s16 Ks[64 * 64];   // [key][hd], swizzled
    __shared__ __align__(16) s16 Vt[64 * 64];   // [hd][key], swizzled
    __shared__ __align__(16) s16 Ps[64 * 64];   // [q][key],  swizzled

    auto swz = [](int row, int col) { return (row * 64 + col) ^ ((row & 7) << 3); };

    const size_t qgrow = (size_t)(b * T_SEQ + qt * 64 + wave * 16 + l15) * (3 * DMODEL) + hoff;
    const bf16x8 qf0 = *reinterpret_cast<const bf16x8*>(&qkv[qgrow + l4 * 8]);
    const bf16x8 qf1 = *reinterpret_cast<const bf16x8*>(&qkv[qgrow + 32 + l4 * 8]);

    f32x4 oacc[4];
    #pragma unroll
    for (int nf = 0; nf < 4; ++nf) oacc[nf] = (f32x4){0.f, 0.f, 0.f, 0.f};
    float m[4] = {-1e30f, -1e30f, -1e30f, -1e30f};
    float l[4] = {0.f, 0.f, 0.f, 0.f};

    const int lo = qt * 64 - window;
    const int cstart = (lo <= 0) ? 0 : (lo >> 6);

    const int kr = tid >> 3;
    const int kc = (tid & 7) * 8;

    for (int c = cstart; c <= qt; ++c) {
        const int j0 = c * 64;
        __syncthreads();
        #pragma unroll
        for (int pass = 0; pass < 2; ++pass) {
            const int row = kr + pass * 32;
            const size_t g = (size_t)(b * T_SEQ + j0 + row) * (3 * DMODEL) + hoff + kc;
            const bf16x8 kv8 = *reinterpret_cast<const bf16x8*>(&qkv[g + DMODEL]);
            const bf16x8 vv8 = *reinterpret_cast<const bf16x8*>(&qkv[g + 2 * DMODEL]);
            *reinterpret_cast<bf16x8*>(&Ks[swz(row, kc)]) = kv8;
            #pragma unroll
            for (int i = 0; i < 8; ++i)
                Vt[swz(kc + i, row)] = vv8[i];   // transpose scatter
        }
        __syncthreads();

        // ---- S = Q @ K^T ----
        f32x4 sacc[4];
        #pragma unroll
        for (int nf = 0; nf < 4; ++nf) sacc[nf] = (f32x4){0.f, 0.f, 0.f, 0.f};
        #pragma unroll
        for (int nf = 0; nf < 4; ++nf) {
            const bf16x8 kf0 = *reinterpret_cast<const bf16x8*>(&Ks[swz(nf * 16 + l15, l4 * 8)]);
            const bf16x8 kf1 = *reinterpret_cast<const bf16x8*>(&Ks[swz(nf * 16 + l15, 32 + l4 * 8)]);
            sacc[nf] = __builtin_amdgcn_mfma_f32_16x16x32_bf16(qf0, kf0, sacc[nf], 0, 0, 0);
            sacc[nf] = __builtin_amdgcn_mfma_f32_16x16x32_bf16(qf1, kf1, sacc[nf], 0, 0, 0);
        }

        // ---- online softmax ----
        float p[4][4];
        #pragma unroll
        for (int r = 0; r < 4; ++r) {
            const int iq = qt * 64 + wave * 16 + l4 * 4 + r;
            float rmax = -1e30f;
            #pragma unroll
            for (int nf = 0; nf < 4; ++nf) {
                const int diff = iq - (j0 + nf * 16 + l15);
                const bool valid = (diff >= 0) && (diff <= window);
                const float s = valid ? sacc[nf][r] * 0.125f : -1e30f;
                p[r][nf] = s;
                rmax = fmaxf(rmax, s);
            }
            rmax = fmaxf(rmax, __shfl_xor(rmax, 1));
            rmax = fmaxf(rmax, __shfl_xor(rmax, 2));
            rmax = fmaxf(rmax, __shfl_xor(rmax, 4));
            rmax = fmaxf(rmax, __shfl_xor(rmax, 8));
            const float mn = fmaxf(m[r], rmax);
            const float rf = __expf(m[r] - mn);
            float rs = 0.f;
            #pragma unroll
            for (int nf = 0; nf < 4; ++nf) {
                const float e = __expf(p[r][nf] - mn);
                p[r][nf] = e;
                rs += e;
            }
            rs += __shfl_xor(rs, 1);
            rs += __shfl_xor(rs, 2);
            rs += __shfl_xor(rs, 4);
            rs += __shfl_xor(rs, 8);
            l[r] = l[r] * rf + rs;
            m[r] = mn;
            #pragma unroll
            for (int nf = 0; nf < 4; ++nf) oacc[nf][r] *= rf;
            #pragma unroll
            for (int nf = 0; nf < 4; ++nf)
                Ps[swz(wave * 16 + l4 * 4 + r, nf * 16 + l15)] = (s16)f2bf(p[r][nf]);
        }
        __syncthreads();

        // ---- O += P @ V ----
        #pragma unroll
        for (int ks = 0; ks < 2; ++ks) {
            const bf16x8 pa = *reinterpret_cast<const bf16x8*>(&Ps[swz(wave * 16 + l15, ks * 32 + l4 * 8)]);
            #pragma unroll
            for (int nf = 0; nf < 4; ++nf) {
                const bf16x8 vf = *reinterpret_cast<const bf16x8*>(&Vt[swz(nf * 16 + l15, ks * 32 + l4 * 8)]);
                oacc[nf] = __builtin_amdgcn_mfma_f32_16x16x32_bf16(pa, vf, oacc[nf], 0, 0, 0);
            }
        }
    }

    #pragma unroll
    for (int r = 0; r < 4; ++r) {
        const float inv = 1.f / l[r];
        const size_t orow = (size_t)(b * T_SEQ + qt * 64 + wave * 16 + l4 * 4 + r) * DMODEL + hoff;
        #pragma unroll
        for (int nf = 0; nf < 4; ++nf)
            out[orow + nf * 16 + l15] = f2bf(oacc[nf][r] * inv);
    }
}

// ---------------------------------------------------------------------------
extern "C" void kernel_launch(void* const* d_in, const int* in_sizes, int n_in,
                              void* d_out, int out_size, void* d_ws, size_t ws_size,
                              hipStream_t stream) {
    (void)in_sizes; (void)n_in; (void)out_size; (void)ws_size;

    const float* x     = (const float*)d_in[0];   // [4096, 1024]
    const float* w_qkv = (const float*)d_in[1];   // [1024, 3072]
    const float* b_qkv = (const float*)d_in[2];   // [3072]
    const float* w_o   = (const float*)d_in[3];   // [1024, 1024]
    const float* b_o   = (const float*)d_in[4];   // [1024]
    const int*   wnd   = (const int*)d_in[5];

    const int M = 2 * T_SEQ;                      // 4096

    // ws layout (bytes): qkvb 24M | attb 8M | xb 8M | wqkvT 6M | woT 2M = 48 MB
    char* w = (char*)d_ws;
    u16* qkvb  = (u16*)(w);
    u16* attb  = (u16*)(w + 24u * 1024 * 1024);
    u16* xb    = (u16*)(w + 32u * 1024 * 1024);
    u16* wqkvT = (u16*)(w + 40u * 1024 * 1024);
    u16* woT   = (u16*)(w + 46u * 1024 * 1024);

    dim3 blk(256);

    // converts (independent)
    convert_kernel<<<dim3((M * DMODEL / 4 + 255) / 256), blk, 0, stream>>>(x, xb, M * DMODEL);
    transpose_convert_kernel<<<dim3(3 * DMODEL / 64, DMODEL / 64), blk, 0, stream>>>(
        w_qkv, wqkvT, DMODEL, 3 * DMODEL);
    transpose_convert_kernel<<<dim3(DMODEL / 64, DMODEL / 64), blk, 0, stream>>>(
        w_o, woT, DMODEL, DMODEL);

    // 1) qkv(bf16) = x @ w_qkv + b_qkv
    gemm_mfma_kernel<128, 128, true><<<dim3(3 * DMODEL / 128, M / 128), blk, 0, stream>>>(
        xb, wqkvT, b_qkv, nullptr, qkvb, M, 3 * DMODEL, DMODEL);

    // 2) banded attention (MFMA)
    swa_mfma_kernel<<<dim3(T_SEQ / 64, 2 * NH), blk, 0, stream>>>(qkvb, attb, wnd);

    // 3) out(fp32) = att @ w_o + b_o
    gemm_mfma_kernel<128, 64, false><<<dim3(DMODEL / 64, M / 128), blk, 0, stream>>>(
        attb, woT, b_o, (float*)d_out, nullptr, M, DMODEL, DMODEL);
}